// Round 12
// baseline (51.662 us; speedup 1.0000x reference)
//
#include <hip/hip_runtime.h>
#include <hip/hip_bf16.h>
#include <hip/hip_fp16.h>
#include <math.h>

#define LRELU_ALPHA 0.2f

typedef __attribute__((ext_vector_type(8))) short bf16x8;
typedef __attribute__((ext_vector_type(4))) float f32x4;
typedef _Float16 f16x8 __attribute__((ext_vector_type(8)));

__device__ __forceinline__ unsigned short f2bf(float f) {
    union { float f; unsigned u; } v; v.f = f;
    unsigned r = v.u + 0x7fffu + ((v.u >> 16) & 1u);
    return (unsigned short)(r >> 16);
}
__device__ __forceinline__ unsigned short f2h(float f) {
    union { __half h; unsigned short s; } c; c.h = __float2half_rn(f); return c.s;
}
__device__ __forceinline__ unsigned cvtpk(float lo, float hi) {
    unsigned r;
    asm("v_cvt_pk_bf16_f32 %0, %1, %2" : "=v"(r) : "v"(lo), "v"(hi));
    return r;
}
__device__ __forceinline__ __half2 u2h2(unsigned u) {
    union { unsigned u; __half2 h; } x; x.u = u; return x.h;
}
__device__ __forceinline__ unsigned h22u(__half2 h) {
    union { __half2 h; unsigned u; } x; x.h = h; return x.u;
}

// ---------------- K0 prep: Wt(f16) + avB(bf16) + edge_out ---------------------------
__global__ void prep_kernel(const float* __restrict__ W,
                            const float* __restrict__ a_pos, const float* __restrict__ a_neg,
                            const float* __restrict__ ee, const float* __restrict__ et,
                            unsigned short* __restrict__ Wt, unsigned short* __restrict__ avB,
                            float* __restrict__ edge_out, int H, int ET) {
    const int HE = H * 4096, AV = H * 256;
    int t = blockIdx.x * blockDim.x + threadIdx.x;
    if (t < HE) {
        int k = t & 63, n = (t >> 6) & 63, h = t >> 12;
        Wt[((size_t)h * 64 + n) * 64 + k] = f2h(W[(size_t)h * 4096 + k * 64 + n]);
    } else if (t < HE + AV) {
        int s = t - HE;
        int k = s & 63, q = (s >> 6) & 3, h = s >> 8;
        const float* a  = (q < 2 ? a_pos : a_neg) + (size_t)h * 128 + (q & 1) * 64;
        const float* wr = W + (size_t)h * 4096 + k * 64;
        float v = 0.f;
#pragma unroll
        for (int o = 0; o < 64; o += 4) {
            const float4 wv = *(const float4*)(wr + o);
            const float4 av = *(const float4*)(a + o);
            v = fmaf(wv.x, av.x, fmaf(wv.y, av.y, fmaf(wv.z, av.z, fmaf(wv.w, av.w, v))));
        }
        avB[((size_t)h * 4 + q) * 64 + k] = f2bf(v);
    } else {
        int s = t - HE - AV;
        if (s < ET * 64) {
            int e = s >> 6, o = s & 63;
            float acc = 0.f;
#pragma unroll
            for (int k = 0; k < 64; ++k)
                acc = fmaf(ee[e * 64 + k], et[k * 64 + o], acc);
            edge_out[s] = acc;
        }
    }
}

// ---------------- K1 (H==4): embed f32->f16 + 16-col score MFMA ---------------------
__global__ __launch_bounds__(256) void score_cvt_kernel(
    const float* __restrict__ nf, const unsigned short* __restrict__ avB,
    const int* __restrict__ un, unsigned short* __restrict__ embed16,
    float2* __restrict__ sc_dst, float2* __restrict__ sc_src, int U)
{
    const int wave = threadIdx.x >> 6;
    const int lane = threadIdx.x & 63;
    const int grp  = lane >> 4;
    const int r    = lane & 15;
    const long u0  = (long)blockIdx.x * 64 + wave * 16;
    if (u0 >= U) return;
    const long u  = u0 + r;
    const long ur = (u < U) ? u : (long)(U - 1);

    const float* erow = nf + (size_t)un[ur] * 64 + grp * 8;
    const float4 e0 = *(const float4*)(erow);
    const float4 e1 = *(const float4*)(erow + 4);
    const float4 e2 = *(const float4*)(erow + 32);
    const float4 e3 = *(const float4*)(erow + 36);

    union { unsigned d[4]; bf16x8 v; } A0, A1;
    A0.d[0] = cvtpk(e0.x, e0.y); A0.d[1] = cvtpk(e0.z, e0.w);
    A0.d[2] = cvtpk(e1.x, e1.y); A0.d[3] = cvtpk(e1.z, e1.w);
    A1.d[0] = cvtpk(e2.x, e2.y); A1.d[1] = cvtpk(e2.z, e2.w);
    A1.d[2] = cvtpk(e3.x, e3.y); A1.d[3] = cvtpk(e3.z, e3.w);

    if (u < U) {
        union { __half2 h2[4]; uint4 v; } F0, F1;
        F0.h2[0] = __floats2half2_rn(e0.x, e0.y); F0.h2[1] = __floats2half2_rn(e0.z, e0.w);
        F0.h2[2] = __floats2half2_rn(e1.x, e1.y); F0.h2[3] = __floats2half2_rn(e1.z, e1.w);
        F1.h2[0] = __floats2half2_rn(e2.x, e2.y); F1.h2[1] = __floats2half2_rn(e2.z, e2.w);
        F1.h2[2] = __floats2half2_rn(e3.x, e3.y); F1.h2[3] = __floats2half2_rn(e3.z, e3.w);
        *(uint4*)(embed16 + (size_t)u * 64 + grp * 8)      = F0.v;
        *(uint4*)(embed16 + (size_t)u * 64 + 32 + grp * 8) = F1.v;
    }

    f32x4 acc = (f32x4)(0.f);
    const unsigned short* wp = avB + (size_t)r * 64 + grp * 8;
    bf16x8 b0 = *(const bf16x8*)wp;
    bf16x8 b1 = *(const bf16x8*)(wp + 32);
    acc = __builtin_amdgcn_mfma_f32_16x16x32_bf16(b0, A0.v, acc, 0, 0, 0);
    acc = __builtin_amdgcn_mfma_f32_16x16x32_bf16(b1, A1.v, acc, 0, 0, 0);

    if (u < U) {
        sc_dst[(size_t)u * 4 + grp] = make_float2(acc[0], acc[2]);   // {pd, nd}
        sc_src[(size_t)u * 4 + grp] = make_float2(acc[1], acc[3]);   // {ps, ns}
    }
}

// ---------------- K2 fused (H==4, DEG 16/16, N%16==0): agg + out GEMM ---------------
// Block = 512 thr (8 waves) = 16 rows. Phase 1: wave w aggregates rows 2w, 2w+1.
// MAC loop: col/att broadcast via register shfl (no LDS round-trip in the address
// chain), uint4 gathers (8 edge-subgroups x 8 chunks x 16B = 1 row/subgroup/instr),
// 5 iters x 2 rows. Agg rows -> LDS with chunk^=(row&7) XOR swizzle.
// Phase 2: waves 0-3 = head h: 16x64 @ 64x64 f16 MFMA from LDS (conflict-free via
// the same swizzle on the read side), relu, store.
__global__ __launch_bounds__(512) void aggemm_kernel(
    const int* __restrict__ pos_col, const int* __restrict__ neg_col,
    const unsigned short* __restrict__ embed16,
    const float2* __restrict__ sc_dst, const float2* __restrict__ sc_src,
    const unsigned short* __restrict__ Wt,
    float* __restrict__ out, int N, int U)
{
    constexpr int DP = 16, NE = 33;
    __shared__ __align__(16) unsigned short s_agg[16][256];  // [row][h*64+dim] f16 (swizzled)

    const int wave = threadIdx.x >> 6;
    const int lane = threadIdx.x & 63;
    const int iA = blockIdx.x * 16 + wave * 2;
    const int iB = iA + 1;

    // ---- cols for both rows (lane = edge id; pads col=0)
    int colA = 0, colB = 0;
    if (lane < DP)       { colA = pos_col[(size_t)iA * DP + lane];
                           colB = pos_col[(size_t)iB * DP + lane]; }
    else if (lane == DP) { colA = pos_col[(size_t)N * DP + iA];
                           colB = pos_col[(size_t)N * DP + iB]; }
    else if (lane < NE)  { colA = neg_col[(size_t)iA * 16 + (lane - DP - 1)];
                           colB = neg_col[(size_t)iB * 16 + (lane - DP - 1)]; }

    // ---- scores (src per lane, dst broadcast from self-edge lane DP)
    const float4* ssv = (const float4*)sc_src;
    const float4 sA0 = ssv[2 * (size_t)(unsigned)colA];
    const float4 sA1 = ssv[2 * (size_t)(unsigned)colA + 1];
    const float4 sB0 = ssv[2 * (size_t)(unsigned)colB];
    const float4 sB1 = ssv[2 * (size_t)(unsigned)colB + 1];
    const int uA = __shfl(colA, DP, 64), uB = __shfl(colB, DP, 64);
    const float4* sdv = (const float4*)sc_dst;
    const float4 dA0 = sdv[2 * (size_t)(unsigned)uA];
    const float4 dA1 = sdv[2 * (size_t)(unsigned)uA + 1];
    const float4 dB0 = sdv[2 * (size_t)(unsigned)uB];
    const float4 dB1 = sdv[2 * (size_t)(unsigned)uB + 1];

    const bool isp = (lane <= DP);
    float a_s0 = isp ? dA0.x + sA0.x : dA0.y + sA0.y;
    float a_s1 = isp ? dA0.z + sA0.z : dA0.w + sA0.w;
    float a_s2 = isp ? dA1.x + sA1.x : dA1.y + sA1.y;
    float a_s3 = isp ? dA1.z + sA1.z : dA1.w + sA1.w;
    float b_s0 = isp ? dB0.x + sB0.x : dB0.y + sB0.y;
    float b_s1 = isp ? dB0.z + sB0.z : dB0.w + sB0.w;
    float b_s2 = isp ? dB1.x + sB1.x : dB1.y + sB1.y;
    float b_s3 = isp ? dB1.z + sB1.z : dB1.w + sB1.w;
    a_s0 = (a_s0 > 0.f) ? a_s0 : LRELU_ALPHA * a_s0;
    a_s1 = (a_s1 > 0.f) ? a_s1 : LRELU_ALPHA * a_s1;
    a_s2 = (a_s2 > 0.f) ? a_s2 : LRELU_ALPHA * a_s2;
    a_s3 = (a_s3 > 0.f) ? a_s3 : LRELU_ALPHA * a_s3;
    b_s0 = (b_s0 > 0.f) ? b_s0 : LRELU_ALPHA * b_s0;
    b_s1 = (b_s1 > 0.f) ? b_s1 : LRELU_ALPHA * b_s1;
    b_s2 = (b_s2 > 0.f) ? b_s2 : LRELU_ALPHA * b_s2;
    b_s3 = (b_s3 > 0.f) ? b_s3 : LRELU_ALPHA * b_s3;

    // exp WITHOUT max-subtract (scores are O(1); f32 exp cannot overflow here)
    const bool act = (lane < NE);
    float ax0 = act ? __expf(a_s0) : 0.f, ax1 = act ? __expf(a_s1) : 0.f;
    float ax2 = act ? __expf(a_s2) : 0.f, ax3 = act ? __expf(a_s3) : 0.f;
    float bx0 = act ? __expf(b_s0) : 0.f, bx1 = act ? __expf(b_s1) : 0.f;
    float bx2 = act ? __expf(b_s2) : 0.f, bx3 = act ? __expf(b_s3) : 0.f;
    float aS0 = ax0, aS1 = ax1, aS2 = ax2, aS3 = ax3;
    float bS0 = bx0, bS1 = bx1, bS2 = bx2, bS3 = bx3;
#pragma unroll
    for (int off = 32; off; off >>= 1) {
        aS0 += __shfl_xor(aS0, off, 64); aS1 += __shfl_xor(aS1, off, 64);
        aS2 += __shfl_xor(aS2, off, 64); aS3 += __shfl_xor(aS3, off, 64);
        bS0 += __shfl_xor(bS0, off, 64); bS1 += __shfl_xor(bS1, off, 64);
        bS2 += __shfl_xor(bS2, off, 64); bS3 += __shfl_xor(bS3, off, 64);
    }
    // packed (att,att) per head, kept in registers; pads are exactly 0
    unsigned aA[4], aB[4];
    aA[0] = h22u(__float2half2_rn(__fdividef(ax0, aS0)));
    aA[1] = h22u(__float2half2_rn(__fdividef(ax1, aS1)));
    aA[2] = h22u(__float2half2_rn(__fdividef(ax2, aS2)));
    aA[3] = h22u(__float2half2_rn(__fdividef(ax3, aS3)));
    aB[0] = h22u(__float2half2_rn(__fdividef(bx0, bS0)));
    aB[1] = h22u(__float2half2_rn(__fdividef(bx1, bS1)));
    aB[2] = h22u(__float2half2_rn(__fdividef(bx2, bS2)));
    aB[3] = h22u(__float2half2_rn(__fdividef(bx3, bS3)));

    // ---- MAC: 5 iters x 2 rows; lane = (sub = edge subgroup 0..7, c = 16B chunk 0..7)
    const int sub = lane >> 3;
    const int c   = lane & 7;
    const char* eb = (const char*)embed16 + (c << 4);
    __half2 accA[4][4], accB[4][4];   // [head][half2-of-chunk]
#pragma unroll
    for (int h = 0; h < 4; ++h)
#pragma unroll
        for (int d = 0; d < 4; ++d) {
            accA[h][d] = __float2half2_rn(0.f);
            accB[h][d] = __float2half2_rn(0.f);
        }
#pragma unroll
    for (int t = 0; t < 5; ++t) {
        const int e  = 8 * t + sub;                       // edge id (pads 33..39: att=0)
        const int cA = __shfl(colA, e, 64);
        const int cB = __shfl(colB, e, 64);
        const uint4 vA = *(const uint4*)(eb + ((size_t)(unsigned)cA << 7));
        const uint4 vB = *(const uint4*)(eb + ((size_t)(unsigned)cB << 7));
#pragma unroll
        for (int h = 0; h < 4; ++h) {
            const __half2 tA = u2h2((unsigned)__shfl((int)aA[h], e, 64));
            const __half2 tB = u2h2((unsigned)__shfl((int)aB[h], e, 64));
            accA[h][0] = __hfma2(tA, u2h2(vA.x), accA[h][0]);
            accA[h][1] = __hfma2(tA, u2h2(vA.y), accA[h][1]);
            accA[h][2] = __hfma2(tA, u2h2(vA.z), accA[h][2]);
            accA[h][3] = __hfma2(tA, u2h2(vA.w), accA[h][3]);
            accB[h][0] = __hfma2(tB, u2h2(vB.x), accB[h][0]);
            accB[h][1] = __hfma2(tB, u2h2(vB.y), accB[h][1]);
            accB[h][2] = __hfma2(tB, u2h2(vB.z), accB[h][2]);
            accB[h][3] = __hfma2(tB, u2h2(vB.w), accB[h][3]);
        }
    }
    // reduce across the 8 edge subgroups (xor lanes 8,16,32)
#pragma unroll
    for (int h = 0; h < 4; ++h)
#pragma unroll
        for (int d = 0; d < 4; ++d) {
            unsigned ua = h22u(accA[h][d]);
            ua = h22u(__hadd2(u2h2(ua), u2h2((unsigned)__shfl_xor((int)ua, 8, 64))));
            ua = h22u(__hadd2(u2h2(ua), u2h2((unsigned)__shfl_xor((int)ua, 16, 64))));
            ua = h22u(__hadd2(u2h2(ua), u2h2((unsigned)__shfl_xor((int)ua, 32, 64))));
            accA[h][d] = u2h2(ua);
            unsigned ub = h22u(accB[h][d]);
            ub = h22u(__hadd2(u2h2(ub), u2h2((unsigned)__shfl_xor((int)ub, 8, 64))));
            ub = h22u(__hadd2(u2h2(ub), u2h2((unsigned)__shfl_xor((int)ub, 16, 64))));
            ub = h22u(__hadd2(u2h2(ub), u2h2((unsigned)__shfl_xor((int)ub, 32, 64))));
            accB[h][d] = u2h2(ub);
        }
    if (sub == 0) {   // lanes 0-7: write swizzled f16 agg rows (chunk c -> c^(row&7))
        const int rA = wave * 2, rB = rA + 1;
#pragma unroll
        for (int h = 0; h < 4; ++h) {
            uint4 wA, wB;
            wA.x = h22u(accA[h][0]); wA.y = h22u(accA[h][1]);
            wA.z = h22u(accA[h][2]); wA.w = h22u(accA[h][3]);
            wB.x = h22u(accB[h][0]); wB.y = h22u(accB[h][1]);
            wB.z = h22u(accB[h][2]); wB.w = h22u(accB[h][3]);
            *(uint4*)((char*)&s_agg[rA][0] + h * 128 + ((c ^ (rA & 7)) << 4)) = wA;
            *(uint4*)((char*)&s_agg[rB][0] + h * 128 + ((c ^ (rB & 7)) << 4)) = wB;
        }
    }
    __syncthreads();

    // ---- phase 2: waves 0-3 = head h; 16 rows x 64 dims f16 MFMA, relu, store
    if (wave < 4) {
        const int h   = wave;
        const int grp = lane >> 4;
        const int r   = lane & 15;
        const char* arow = (const char*)&s_agg[r][0] + h * 128;
        const f16x8 a0 = *(const f16x8*)(arow + ((grp       ^ (r & 7)) << 4));
        const f16x8 a1 = *(const f16x8*)(arow + (((4 + grp) ^ (r & 7)) << 4));
        f32x4 acc[4];
#pragma unroll
        for (int nt = 0; nt < 4; ++nt) {
            acc[nt] = (f32x4)(0.f);
            const unsigned short* wp = Wt + (((size_t)h * 64 + nt * 16 + r) * 64 + grp * 8);
            const f16x8 b0 = *(const f16x8*)wp;
            const f16x8 b1 = *(const f16x8*)(wp + 32);
            acc[nt] = __builtin_amdgcn_mfma_f32_16x16x32_f16(b0, a0, acc[nt], 0, 0, 0);
            acc[nt] = __builtin_amdgcn_mfma_f32_16x16x32_f16(b1, a1, acc[nt], 0, 0, 0);
        }
        float* orow = out + ((size_t)(blockIdx.x * 16 + r) * 4 + h) * 64;
#pragma unroll
        for (int nt = 0; nt < 4; ++nt) {
            float4 o;
            o.x = fmaxf(acc[nt][0], 0.f); o.y = fmaxf(acc[nt][1], 0.f);
            o.z = fmaxf(acc[nt][2], 0.f); o.w = fmaxf(acc[nt][3], 0.f);
            *(float4*)(orow + nt * 16 + grp * 4) = o;
        }
    }
}

// ---------------- generic fallbacks (correctness-only, any shape) -------------------
__global__ void embed_cvt_generic(const float* __restrict__ nf, const int* __restrict__ un,
                                  unsigned short* __restrict__ embed16, int U) {
    long t = (long)blockIdx.x * blockDim.x + threadIdx.x;
    if (t >= (long)U * 64) return;
    embed16[t] = f2h(nf[(size_t)un[t >> 6] * 64 + (t & 63)]);
}
__global__ void score_generic(const unsigned short* __restrict__ embed16,
                              const unsigned short* __restrict__ avB,
                              float2* __restrict__ sc_dst, float2* __restrict__ sc_src,
                              int U, int H) {
    long t = (long)blockIdx.x * blockDim.x + threadIdx.x;
    if (t >= (long)U * H) return;
    const long u = t / H; const int h = (int)(t % H);
    float s[4];
    for (int q = 0; q < 4; ++q) {
        float acc = 0.f;
        for (int k = 0; k < 64; ++k) {
            union { unsigned short s; __half h; } w; w.s = embed16[u * 64 + k];
            union { unsigned u; float f; } b; b.u = ((unsigned)avB[((size_t)h * 4 + q) * 64 + k]) << 16;
            acc = fmaf(__half2float(w.h), b.f, acc);
        }
        s[q] = acc;
    }
    sc_dst[u * H + h] = make_float2(s[0], s[2]);
    sc_src[u * H + h] = make_float2(s[1], s[3]);
}
__global__ __launch_bounds__(256) void agg_generic(
    const int* __restrict__ pos_col, const int* __restrict__ neg_col,
    const unsigned short* __restrict__ embed16,
    const float2* __restrict__ sc_dst, const float2* __restrict__ sc_src,
    unsigned short* __restrict__ aggb, int N, int U, int DEGP, int DEGN, int H)
{
    const int wave = threadIdx.x >> 6;
    const int lane = threadIdx.x & 63;
    const long j = (long)blockIdx.x * 4 + wave;
    const int i = (int)(j % N);
    const int h = (int)(j / N);
    if (h >= H) return;
    const int NE = DEGP + 1 + DEGN;

    int col = 0;
    if (lane < DEGP)       col = pos_col[(size_t)i * DEGP + lane];
    else if (lane == DEGP) col = pos_col[(size_t)N * DEGP + i];
    else if (lane < NE)    col = neg_col[(size_t)i * DEGN + (lane - DEGP - 1)];
    const float2 ss = sc_src[(size_t)col * H + h];
    const int u0s = __shfl(col, DEGP, 64);
    const float2 sd = sc_dst[(size_t)u0s * H + h];
    float score = -INFINITY;
    if (lane < NE) {
        const float raw = (lane <= DEGP) ? sd.x + ss.x : sd.y + ss.y;
        score = (raw > 0.f) ? raw : LRELU_ALPHA * raw;
    }
    float m = score;
#pragma unroll
    for (int off = 32; off; off >>= 1) m = fmaxf(m, __shfl_xor(m, off, 64));
    const float ex = (lane < NE) ? __expf(score - m) : 0.f;
    float S = ex;
#pragma unroll
    for (int off = 32; off; off >>= 1) S += __shfl_xor(S, off, 64);
    const float att = __fdividef(ex, S);

    float acc = 0.f;
    for (int e = 0; e < NE; ++e) {
        const int   ce = __shfl(col, e, 64);
        const float ae = __shfl(att, e, 64);
        union { unsigned short s; __half h; } w; w.s = embed16[(size_t)(unsigned)ce * 64 + lane];
        acc = fmaf(ae, __half2float(w.h), acc);
    }
    aggb[((size_t)i * H + h) * 64 + lane] = f2h(acc);
}
__global__ __launch_bounds__(256) void out_gemm_generic(
    const unsigned short* __restrict__ aggb, const unsigned short* __restrict__ Wt,
    float* __restrict__ out, int N, int H)
{
    const int wave = threadIdx.x >> 6;
    const int lane = threadIdx.x & 63;
    const int grp  = lane >> 4;
    const int r    = lane & 15;
    const long j = (long)blockIdx.x * 4 + wave;
    const int  h = (int)(j % H);
    const long i0 = (j / H) * 16;
    if (i0 >= N) return;
    const long i  = i0 + r;
    const long ir = (i < N) ? i : (long)(N - 1);

    const unsigned short* arow = aggb + ((size_t)ir * H + h) * 64 + grp * 8;
    const f16x8 a0 = *(const f16x8*)arow;
    const f16x8 a1 = *(const f16x8*)(arow + 32);
    f32x4 acc[4];
#pragma unroll
    for (int nt = 0; nt < 4; ++nt) {
        acc[nt] = (f32x4)(0.f);
        const unsigned short* wp = Wt + (((size_t)h * 64 + nt * 16 + r) * 64 + grp * 8);
        const f16x8 b0 = *(const f16x8*)wp;
        const f16x8 b1 = *(const f16x8*)(wp + 32);
        acc[nt] = __builtin_amdgcn_mfma_f32_16x16x32_f16(b0, a0, acc[nt], 0, 0, 0);
        acc[nt] = __builtin_amdgcn_mfma_f32_16x16x32_f16(b1, a1, acc[nt], 0, 0, 0);
    }
    if (i < N) {
        float* orow = out + ((size_t)i * H + h) * 64;
#pragma unroll
        for (int nt = 0; nt < 4; ++nt) {
            float4 o;
            o.x = fmaxf(acc[nt][0], 0.f); o.y = fmaxf(acc[nt][1], 0.f);
            o.z = fmaxf(acc[nt][2], 0.f); o.w = fmaxf(acc[nt][3], 0.f);
            *(float4*)(orow + nt * 16 + grp * 4) = o;
        }
    }
}

extern "C" void kernel_launch(void* const* d_in, const int* in_sizes, int n_in,
                              void* d_out, int out_size, void* d_ws, size_t ws_size,
                              hipStream_t stream) {
    const float* nf     = (const float*)d_in[0];
    const float* W      = (const float*)d_in[1];
    const float* a_pos  = (const float*)d_in[2];
    const float* a_neg  = (const float*)d_in[3];
    const float* ee     = (const float*)d_in[4];
    const float* et     = (const float*)d_in[5];
    const int* unique_nodes = (const int*)d_in[6];
    const int* pos_col  = (const int*)d_in[9];
    const int* neg_col  = (const int*)d_in[11];

    const int U    = in_sizes[6];
    const int N    = in_sizes[7];
    const int Epos = in_sizes[8];
    const int Eneg = in_sizes[10];
    const int H    = in_sizes[1] / (64 * 64);
    const int DEGN = Eneg / N;
    const int DEGP = Epos / N - 1;
    const int ET   = in_sizes[4] / 64;

    char* ws = (char*)d_ws;
    auto alloc = [&](size_t bytes) { char* p = ws; ws += (bytes + 255) & ~(size_t)255; return p; };
    unsigned short* embed16 = (unsigned short*)alloc((size_t)U * 64 * 2);
    float2*         sc_dst  = (float2*)alloc((size_t)U * H * 8);
    float2*         sc_src  = (float2*)alloc((size_t)U * H * 8);
    unsigned short* aggb    = (unsigned short*)alloc((size_t)N * H * 64 * 2);
    unsigned short* Wt      = (unsigned short*)alloc((size_t)H * 4096 * 2);
    unsigned short* avB     = (unsigned short*)alloc((size_t)H * 256 * 2);
    float* out = (float*)d_out;

    const int PT = H * 4096 + H * 256 + ET * 64;
    prep_kernel<<<(PT + 255) / 256, 256, 0, stream>>>(W, a_pos, a_neg, ee, et, Wt, avB,
                                                      out + (size_t)N * H * 64, H, ET);

    if (H == 4 && DEGP == 16 && DEGN == 16 && (N % 16) == 0) {
        score_cvt_kernel<<<(U + 63) / 64, 256, 0, stream>>>(nf, avB, unique_nodes,
                                                            embed16, sc_dst, sc_src, U);
        aggemm_kernel<<<N / 16, 512, 0, stream>>>(pos_col, neg_col, embed16,
                                                  sc_dst, sc_src, Wt, out, N, U);
    } else {
        embed_cvt_generic<<<(int)(((long)U * 64 + 255) / 256), 256, 0, stream>>>(
            nf, unique_nodes, embed16, U);
        score_generic<<<(int)(((long)U * H + 255) / 256), 256, 0, stream>>>(
            embed16, avB, sc_dst, sc_src, U, H);
        agg_generic<<<(int)(((long)N * H + 3) / 4), 256, 0, stream>>>(
            pos_col, neg_col, embed16, sc_dst, sc_src, aggb, N, U, DEGP, DEGN, H);
        const long tiles = ((long)N + 15) / 16;
        out_gemm_generic<<<(int)((tiles * H + 3) / 4), 256, 0, stream>>>(aggb, Wt, out, N, H);
    }
}

// Round 13
// 50.265 us; speedup vs baseline: 1.0278x; 1.0278x over previous
//
#include <hip/hip_runtime.h>
#include <hip/hip_bf16.h>
#include <hip/hip_fp16.h>
#include <math.h>

#define LRELU_ALPHA 0.2f

typedef __attribute__((ext_vector_type(8))) short bf16x8;
typedef __attribute__((ext_vector_type(4))) float f32x4;
typedef _Float16 f16x8 __attribute__((ext_vector_type(8)));

__device__ __forceinline__ unsigned short f2bf(float f) {
    union { float f; unsigned u; } v; v.f = f;
    unsigned r = v.u + 0x7fffu + ((v.u >> 16) & 1u);
    return (unsigned short)(r >> 16);
}
__device__ __forceinline__ unsigned short f2h(float f) {
    union { __half h; unsigned short s; } c; c.h = __float2half_rn(f); return c.s;
}
__device__ __forceinline__ unsigned cvtpk(float lo, float hi) {
    unsigned r;
    asm("v_cvt_pk_bf16_f32 %0, %1, %2" : "=v"(r) : "v"(lo), "v"(hi));
    return r;
}
__device__ __forceinline__ __half2 u2h2(unsigned u) {
    union { unsigned u; __half2 h; } x; x.u = u; return x.h;
}
__device__ __forceinline__ unsigned h22u(__half2 h) {
    union { __half2 h; unsigned u; } x; x.h = h; return x.u;
}

// ---------------- K0 prep: Wt(f16) + avB(bf16) + edge_out ---------------------------
__global__ void prep_kernel(const float* __restrict__ W,
                            const float* __restrict__ a_pos, const float* __restrict__ a_neg,
                            const float* __restrict__ ee, const float* __restrict__ et,
                            unsigned short* __restrict__ Wt, unsigned short* __restrict__ avB,
                            float* __restrict__ edge_out, int H, int ET) {
    const int HE = H * 4096, AV = H * 256;
    int t = blockIdx.x * blockDim.x + threadIdx.x;
    if (t < HE) {
        int k = t & 63, n = (t >> 6) & 63, h = t >> 12;
        Wt[((size_t)h * 64 + n) * 64 + k] = f2h(W[(size_t)h * 4096 + k * 64 + n]);
    } else if (t < HE + AV) {
        int s = t - HE;
        int k = s & 63, q = (s >> 6) & 3, h = s >> 8;
        const float* a  = (q < 2 ? a_pos : a_neg) + (size_t)h * 128 + (q & 1) * 64;
        const float* wr = W + (size_t)h * 4096 + k * 64;
        float v = 0.f;
#pragma unroll
        for (int o = 0; o < 64; o += 4) {
            const float4 wv = *(const float4*)(wr + o);
            const float4 av = *(const float4*)(a + o);
            v = fmaf(wv.x, av.x, fmaf(wv.y, av.y, fmaf(wv.z, av.z, fmaf(wv.w, av.w, v))));
        }
        avB[((size_t)h * 4 + q) * 64 + k] = f2bf(v);
    } else {
        int s = t - HE - AV;
        if (s < ET * 64) {
            int e = s >> 6, o = s & 63;
            float acc = 0.f;
#pragma unroll
            for (int k = 0; k < 64; ++k)
                acc = fmaf(ee[e * 64 + k], et[k * 64 + o], acc);
            edge_out[s] = acc;
        }
    }
}

// ---------------- K1 (H==4): embed f32->f16 (split lo/hi slabs) + score MFMA --------
// elo[u][32] = dims 0..31, ehi[u][32] = dims 32..63  (3.2MB each -> fits per-XCD L2)
__global__ __launch_bounds__(256) void score_cvt_kernel(
    const float* __restrict__ nf, const unsigned short* __restrict__ avB,
    const int* __restrict__ un, unsigned short* __restrict__ elo,
    unsigned short* __restrict__ ehi,
    float2* __restrict__ sc_dst, float2* __restrict__ sc_src, int U)
{
    const int wave = threadIdx.x >> 6;
    const int lane = threadIdx.x & 63;
    const int grp  = lane >> 4;
    const int r    = lane & 15;
    const long u0  = (long)blockIdx.x * 64 + wave * 16;
    if (u0 >= U) return;
    const long u  = u0 + r;
    const long ur = (u < U) ? u : (long)(U - 1);

    const float* erow = nf + (size_t)un[ur] * 64 + grp * 8;
    const float4 e0 = *(const float4*)(erow);
    const float4 e1 = *(const float4*)(erow + 4);
    const float4 e2 = *(const float4*)(erow + 32);
    const float4 e3 = *(const float4*)(erow + 36);

    union { unsigned d[4]; bf16x8 v; } A0, A1;
    A0.d[0] = cvtpk(e0.x, e0.y); A0.d[1] = cvtpk(e0.z, e0.w);
    A0.d[2] = cvtpk(e1.x, e1.y); A0.d[3] = cvtpk(e1.z, e1.w);
    A1.d[0] = cvtpk(e2.x, e2.y); A1.d[1] = cvtpk(e2.z, e2.w);
    A1.d[2] = cvtpk(e3.x, e3.y); A1.d[3] = cvtpk(e3.z, e3.w);

    if (u < U) {
        union { __half2 h2[4]; uint4 v; } F0, F1;
        F0.h2[0] = __floats2half2_rn(e0.x, e0.y); F0.h2[1] = __floats2half2_rn(e0.z, e0.w);
        F0.h2[2] = __floats2half2_rn(e1.x, e1.y); F0.h2[3] = __floats2half2_rn(e1.z, e1.w);
        F1.h2[0] = __floats2half2_rn(e2.x, e2.y); F1.h2[1] = __floats2half2_rn(e2.z, e2.w);
        F1.h2[2] = __floats2half2_rn(e3.x, e3.y); F1.h2[3] = __floats2half2_rn(e3.z, e3.w);
        *(uint4*)(elo + (size_t)u * 32 + grp * 8) = F0.v;   // dims grp*8..+7
        *(uint4*)(ehi + (size_t)u * 32 + grp * 8) = F1.v;   // dims 32+grp*8..+7
    }

    f32x4 acc = (f32x4)(0.f);
    const unsigned short* wp = avB + (size_t)r * 64 + grp * 8;
    bf16x8 b0 = *(const bf16x8*)wp;
    bf16x8 b1 = *(const bf16x8*)(wp + 32);
    acc = __builtin_amdgcn_mfma_f32_16x16x32_bf16(b0, A0.v, acc, 0, 0, 0);
    acc = __builtin_amdgcn_mfma_f32_16x16x32_bf16(b1, A1.v, acc, 0, 0, 0);

    if (u < U) {
        sc_dst[(size_t)u * 4 + grp] = make_float2(acc[0], acc[2]);   // {pd, nd}
        sc_src[(size_t)u * 4 + grp] = make_float2(acc[1], acc[3]);   // {ps, ns}
    }
}

// ---------------- K2 fused (H==4, DEG 16/16, N%16==0): agg (2 half-passes) + GEMM ---
// Block = 512 thr (8 waves) = 16 rows, wave = 2 rows. Softmax once -> LDS col/att
// tables. MAC runs TWO passes: pass 0 gathers from elo (3.2MB slab), pass 1 from ehi,
// __syncthreads between passes so each XCD's L2 holds mostly one slab at a time.
// Per pass: 5 iters, lane=(sub=edge 0..7, c=8B chunk 0..7), uint2 loads (64B rows).
// Phase 2: waves 0-3 = head h: 16x64 @ 64x64 f16 MFMA from LDS, relu, store.
__global__ __launch_bounds__(512) void aggemm_kernel(
    const int* __restrict__ pos_col, const int* __restrict__ neg_col,
    const unsigned short* __restrict__ elo, const unsigned short* __restrict__ ehi,
    const float2* __restrict__ sc_dst, const float2* __restrict__ sc_src,
    const unsigned short* __restrict__ Wt,
    float* __restrict__ out, int N, int U)
{
    constexpr int DP = 16, NE = 33, NEP = 40;
    __shared__ int   s_col[8][2][NEP];
    __shared__ uint4 s_att[8][2][NEP];
    __shared__ __align__(16) unsigned short s_agg[16][256];  // [row][h*64+dim] f16

    const int wave = threadIdx.x >> 6;
    const int lane = threadIdx.x & 63;
    const int iA = blockIdx.x * 16 + wave * 2;
    const int iB = iA + 1;

    // ---- cols for both rows (lane = edge id; pads col=0)
    int colA = 0, colB = 0;
    if (lane < DP)       { colA = pos_col[(size_t)iA * DP + lane];
                           colB = pos_col[(size_t)iB * DP + lane]; }
    else if (lane == DP) { colA = pos_col[(size_t)N * DP + iA];
                           colB = pos_col[(size_t)N * DP + iB]; }
    else if (lane < NE)  { colA = neg_col[(size_t)iA * 16 + (lane - DP - 1)];
                           colB = neg_col[(size_t)iB * 16 + (lane - DP - 1)]; }

    // ---- scores (src per lane, dst broadcast from self-edge lane DP)
    const float4* ssv = (const float4*)sc_src;
    const float4 sA0 = ssv[2 * (size_t)(unsigned)colA];
    const float4 sA1 = ssv[2 * (size_t)(unsigned)colA + 1];
    const float4 sB0 = ssv[2 * (size_t)(unsigned)colB];
    const float4 sB1 = ssv[2 * (size_t)(unsigned)colB + 1];
    const int uA = __shfl(colA, DP, 64), uB = __shfl(colB, DP, 64);
    const float4* sdv = (const float4*)sc_dst;
    const float4 dA0 = sdv[2 * (size_t)(unsigned)uA];
    const float4 dA1 = sdv[2 * (size_t)(unsigned)uA + 1];
    const float4 dB0 = sdv[2 * (size_t)(unsigned)uB];
    const float4 dB1 = sdv[2 * (size_t)(unsigned)uB + 1];

    const bool isp = (lane <= DP);
    float a_s0 = isp ? dA0.x + sA0.x : dA0.y + sA0.y;
    float a_s1 = isp ? dA0.z + sA0.z : dA0.w + sA0.w;
    float a_s2 = isp ? dA1.x + sA1.x : dA1.y + sA1.y;
    float a_s3 = isp ? dA1.z + sA1.z : dA1.w + sA1.w;
    float b_s0 = isp ? dB0.x + sB0.x : dB0.y + sB0.y;
    float b_s1 = isp ? dB0.z + sB0.z : dB0.w + sB0.w;
    float b_s2 = isp ? dB1.x + sB1.x : dB1.y + sB1.y;
    float b_s3 = isp ? dB1.z + sB1.z : dB1.w + sB1.w;
    a_s0 = (a_s0 > 0.f) ? a_s0 : LRELU_ALPHA * a_s0;
    a_s1 = (a_s1 > 0.f) ? a_s1 : LRELU_ALPHA * a_s1;
    a_s2 = (a_s2 > 0.f) ? a_s2 : LRELU_ALPHA * a_s2;
    a_s3 = (a_s3 > 0.f) ? a_s3 : LRELU_ALPHA * a_s3;
    b_s0 = (b_s0 > 0.f) ? b_s0 : LRELU_ALPHA * b_s0;
    b_s1 = (b_s1 > 0.f) ? b_s1 : LRELU_ALPHA * b_s1;
    b_s2 = (b_s2 > 0.f) ? b_s2 : LRELU_ALPHA * b_s2;
    b_s3 = (b_s3 > 0.f) ? b_s3 : LRELU_ALPHA * b_s3;

    // exp WITHOUT max-subtract (scores are O(1); f32 exp cannot overflow here)
    const bool act = (lane < NE);
    float ax0 = act ? __expf(a_s0) : 0.f, ax1 = act ? __expf(a_s1) : 0.f;
    float ax2 = act ? __expf(a_s2) : 0.f, ax3 = act ? __expf(a_s3) : 0.f;
    float bx0 = act ? __expf(b_s0) : 0.f, bx1 = act ? __expf(b_s1) : 0.f;
    float bx2 = act ? __expf(b_s2) : 0.f, bx3 = act ? __expf(b_s3) : 0.f;
    float aS0 = ax0, aS1 = ax1, aS2 = ax2, aS3 = ax3;
    float bS0 = bx0, bS1 = bx1, bS2 = bx2, bS3 = bx3;
#pragma unroll
    for (int off = 32; off; off >>= 1) {
        aS0 += __shfl_xor(aS0, off, 64); aS1 += __shfl_xor(aS1, off, 64);
        aS2 += __shfl_xor(aS2, off, 64); aS3 += __shfl_xor(aS3, off, 64);
        bS0 += __shfl_xor(bS0, off, 64); bS1 += __shfl_xor(bS1, off, 64);
        bS2 += __shfl_xor(bS2, off, 64); bS3 += __shfl_xor(bS3, off, 64);
    }
    if (lane < NEP) {   // lanes 33..39: col=0, att=0
        uint4 tA, tB;
        tA.x = h22u(__float2half2_rn(__fdividef(ax0, aS0)));
        tA.y = h22u(__float2half2_rn(__fdividef(ax1, aS1)));
        tA.z = h22u(__float2half2_rn(__fdividef(ax2, aS2)));
        tA.w = h22u(__float2half2_rn(__fdividef(ax3, aS3)));
        tB.x = h22u(__float2half2_rn(__fdividef(bx0, bS0)));
        tB.y = h22u(__float2half2_rn(__fdividef(bx1, bS1)));
        tB.z = h22u(__float2half2_rn(__fdividef(bx2, bS2)));
        tB.w = h22u(__float2half2_rn(__fdividef(bx3, bS3)));
        s_col[wave][0][lane] = colA;  s_att[wave][0][lane] = tA;
        s_col[wave][1][lane] = colB;  s_att[wave][1][lane] = tB;
    }
    // wave-private LDS slice: same-wave ordering, no barrier needed

    // ---- MAC: two half-dim passes (elo then ehi), each a 3.2MB L2-resident slab
    const int sub = lane >> 3;          // edge subgroup 0..7
    const int c   = lane & 7;           // 8B chunk 0..7 of a 64B half-row
    const int rA  = wave * 2, rB = rA + 1;
#pragma unroll
    for (int half = 0; half < 2; ++half) {
        const char* eb = (const char*)(half ? ehi : elo) + (c << 3);
        __half2 accA[4][2], accB[4][2];   // [head][half2 within 8B chunk]
#pragma unroll
        for (int h = 0; h < 4; ++h)
#pragma unroll
            for (int d = 0; d < 2; ++d) {
                accA[h][d] = __float2half2_rn(0.f);
                accB[h][d] = __float2half2_rn(0.f);
            }
#pragma unroll
        for (int t = 0; t < 5; ++t) {
            const int e  = 8 * t + sub;
            const int cA = s_col[wave][0][e];
            const int cB = s_col[wave][1][e];
            const uint2 vA = *(const uint2*)(eb + ((size_t)(unsigned)cA << 6));
            const uint2 vB = *(const uint2*)(eb + ((size_t)(unsigned)cB << 6));
            const uint4 aA = s_att[wave][0][e];
            const uint4 aB = s_att[wave][1][e];
            const __half2 vA0 = u2h2(vA.x), vA1 = u2h2(vA.y);
            const __half2 vB0 = u2h2(vB.x), vB1 = u2h2(vB.y);
            accA[0][0] = __hfma2(u2h2(aA.x), vA0, accA[0][0]);
            accA[0][1] = __hfma2(u2h2(aA.x), vA1, accA[0][1]);
            accA[1][0] = __hfma2(u2h2(aA.y), vA0, accA[1][0]);
            accA[1][1] = __hfma2(u2h2(aA.y), vA1, accA[1][1]);
            accA[2][0] = __hfma2(u2h2(aA.z), vA0, accA[2][0]);
            accA[2][1] = __hfma2(u2h2(aA.z), vA1, accA[2][1]);
            accA[3][0] = __hfma2(u2h2(aA.w), vA0, accA[3][0]);
            accA[3][1] = __hfma2(u2h2(aA.w), vA1, accA[3][1]);
            accB[0][0] = __hfma2(u2h2(aB.x), vB0, accB[0][0]);
            accB[0][1] = __hfma2(u2h2(aB.x), vB1, accB[0][1]);
            accB[1][0] = __hfma2(u2h2(aB.y), vB0, accB[1][0]);
            accB[1][1] = __hfma2(u2h2(aB.y), vB1, accB[1][1]);
            accB[2][0] = __hfma2(u2h2(aB.z), vB0, accB[2][0]);
            accB[2][1] = __hfma2(u2h2(aB.z), vB1, accB[2][1]);
            accB[3][0] = __hfma2(u2h2(aB.w), vB0, accB[3][0]);
            accB[3][1] = __hfma2(u2h2(aB.w), vB1, accB[3][1]);
        }
        // reduce across the 8 edge subgroups (xor lanes 8,16,32)
#pragma unroll
        for (int h = 0; h < 4; ++h)
#pragma unroll
            for (int d = 0; d < 2; ++d) {
                unsigned ua = h22u(accA[h][d]);
                ua = h22u(__hadd2(u2h2(ua), u2h2((unsigned)__shfl_xor((int)ua, 8, 64))));
                ua = h22u(__hadd2(u2h2(ua), u2h2((unsigned)__shfl_xor((int)ua, 16, 64))));
                ua = h22u(__hadd2(u2h2(ua), u2h2((unsigned)__shfl_xor((int)ua, 32, 64))));
                accA[h][d] = u2h2(ua);
                unsigned ub = h22u(accB[h][d]);
                ub = h22u(__hadd2(u2h2(ub), u2h2((unsigned)__shfl_xor((int)ub, 8, 64))));
                ub = h22u(__hadd2(u2h2(ub), u2h2((unsigned)__shfl_xor((int)ub, 16, 64))));
                ub = h22u(__hadd2(u2h2(ub), u2h2((unsigned)__shfl_xor((int)ub, 32, 64))));
                accB[h][d] = u2h2(ub);
            }
        if (sub == 0) {   // lanes 0-7 write dims half*32 + c*4 .. +3 per head
#pragma unroll
            for (int h = 0; h < 4; ++h) {
                uint2 wA, wB;
                wA.x = h22u(accA[h][0]); wA.y = h22u(accA[h][1]);
                wB.x = h22u(accB[h][0]); wB.y = h22u(accB[h][1]);
                *(uint2*)((char*)&s_agg[rA][0] + h * 128 + half * 64 + (c << 3)) = wA;
                *(uint2*)((char*)&s_agg[rB][0] + h * 128 + half * 64 + (c << 3)) = wB;
            }
        }
        __syncthreads();   // phase separation: keep the XCD's L2 on one slab at a time
    }

    // ---- phase 2: waves 0-3 = head h; 16 rows x 64 dims f16 MFMA, relu, store
    if (wave < 4) {
        const int h   = wave;
        const int grp = lane >> 4;
        const int r   = lane & 15;
        const f16x8 a0 = *(const f16x8*)((const char*)&s_agg[r][0] + h * 128 + grp * 16);
        const f16x8 a1 = *(const f16x8*)((const char*)&s_agg[r][0] + h * 128 + 64 + grp * 16);
        f32x4 acc[4];
#pragma unroll
        for (int nt = 0; nt < 4; ++nt) {
            acc[nt] = (f32x4)(0.f);
            const unsigned short* wp = Wt + (((size_t)h * 64 + nt * 16 + r) * 64 + grp * 8);
            const f16x8 b0 = *(const f16x8*)wp;
            const f16x8 b1 = *(const f16x8*)(wp + 32);
            acc[nt] = __builtin_amdgcn_mfma_f32_16x16x32_f16(b0, a0, acc[nt], 0, 0, 0);
            acc[nt] = __builtin_amdgcn_mfma_f32_16x16x32_f16(b1, a1, acc[nt], 0, 0, 0);
        }
        float* orow = out + ((size_t)(blockIdx.x * 16 + r) * 4 + h) * 64;
#pragma unroll
        for (int nt = 0; nt < 4; ++nt) {
            float4 o;
            o.x = fmaxf(acc[nt][0], 0.f); o.y = fmaxf(acc[nt][1], 0.f);
            o.z = fmaxf(acc[nt][2], 0.f); o.w = fmaxf(acc[nt][3], 0.f);
            *(float4*)(orow + nt * 16 + grp * 4) = o;
        }
    }
}

// ---------------- generic fallbacks (correctness-only, any shape) -------------------
__global__ void embed_cvt_generic(const float* __restrict__ nf, const int* __restrict__ un,
                                  unsigned short* __restrict__ elo,
                                  unsigned short* __restrict__ ehi, int U) {
    long t = (long)blockIdx.x * blockDim.x + threadIdx.x;
    if (t >= (long)U * 64) return;
    const long u = t >> 6; const int dim = (int)(t & 63);
    const unsigned short v = f2h(nf[(size_t)un[u] * 64 + dim]);
    if (dim < 32) elo[u * 32 + dim] = v;
    else          ehi[u * 32 + dim - 32] = v;
}
__device__ __forceinline__ float emb_at(const unsigned short* elo, const unsigned short* ehi,
                                        long u, int k) {
    union { unsigned short s; __half h; } w;
    w.s = (k < 32) ? elo[u * 32 + k] : ehi[u * 32 + k - 32];
    return __half2float(w.h);
}
__global__ void score_generic(const unsigned short* __restrict__ elo,
                              const unsigned short* __restrict__ ehi,
                              const unsigned short* __restrict__ avB,
                              float2* __restrict__ sc_dst, float2* __restrict__ sc_src,
                              int U, int H) {
    long t = (long)blockIdx.x * blockDim.x + threadIdx.x;
    if (t >= (long)U * H) return;
    const long u = t / H; const int h = (int)(t % H);
    float s[4];
    for (int q = 0; q < 4; ++q) {
        float acc = 0.f;
        for (int k = 0; k < 64; ++k) {
            union { unsigned uu; float f; } b;
            b.uu = ((unsigned)avB[((size_t)h * 4 + q) * 64 + k]) << 16;
            acc = fmaf(emb_at(elo, ehi, u, k), b.f, acc);
        }
        s[q] = acc;
    }
    sc_dst[u * H + h] = make_float2(s[0], s[2]);
    sc_src[u * H + h] = make_float2(s[1], s[3]);
}
__global__ __launch_bounds__(256) void agg_generic(
    const int* __restrict__ pos_col, const int* __restrict__ neg_col,
    const unsigned short* __restrict__ elo, const unsigned short* __restrict__ ehi,
    const float2* __restrict__ sc_dst, const float2* __restrict__ sc_src,
    unsigned short* __restrict__ aggb, int N, int U, int DEGP, int DEGN, int H)
{
    const int wave = threadIdx.x >> 6;
    const int lane = threadIdx.x & 63;
    const long j = (long)blockIdx.x * 4 + wave;
    const int i = (int)(j % N);
    const int h = (int)(j / N);
    if (h >= H) return;
    const int NE = DEGP + 1 + DEGN;

    int col = 0;
    if (lane < DEGP)       col = pos_col[(size_t)i * DEGP + lane];
    else if (lane == DEGP) col = pos_col[(size_t)N * DEGP + i];
    else if (lane < NE)    col = neg_col[(size_t)i * DEGN + (lane - DEGP - 1)];
    const float2 ss = sc_src[(size_t)col * H + h];
    const int u0s = __shfl(col, DEGP, 64);
    const float2 sd = sc_dst[(size_t)u0s * H + h];
    float score = -INFINITY;
    if (lane < NE) {
        const float raw = (lane <= DEGP) ? sd.x + ss.x : sd.y + ss.y;
        score = (raw > 0.f) ? raw : LRELU_ALPHA * raw;
    }
    float m = score;
#pragma unroll
    for (int off = 32; off; off >>= 1) m = fmaxf(m, __shfl_xor(m, off, 64));
    const float ex = (lane < NE) ? __expf(score - m) : 0.f;
    float S = ex;
#pragma unroll
    for (int off = 32; off; off >>= 1) S += __shfl_xor(S, off, 64);
    const float att = __fdividef(ex, S);

    float acc = 0.f;
    for (int e = 0; e < NE; ++e) {
        const int   ce = __shfl(col, e, 64);
        const float ae = __shfl(att, e, 64);
        acc = fmaf(ae, emb_at(elo, ehi, (long)(unsigned)ce, lane), acc);
    }
    aggb[((size_t)i * H + h) * 64 + lane] = f2h(acc);
}
__global__ __launch_bounds__(256) void out_gemm_generic(
    const unsigned short* __restrict__ aggb, const unsigned short* __restrict__ Wt,
    float* __restrict__ out, int N, int H)
{
    const int wave = threadIdx.x >> 6;
    const int lane = threadIdx.x & 63;
    const int grp  = lane >> 4;
    const int r    = lane & 15;
    const long j = (long)blockIdx.x * 4 + wave;
    const int  h = (int)(j % H);
    const long i0 = (j / H) * 16;
    if (i0 >= N) return;
    const long i  = i0 + r;
    const long ir = (i < N) ? i : (long)(N - 1);

    const unsigned short* arow = aggb + ((size_t)ir * H + h) * 64 + grp * 8;
    const f16x8 a0 = *(const f16x8*)arow;
    const f16x8 a1 = *(const f16x8*)(arow + 32);
    f32x4 acc[4];
#pragma unroll
    for (int nt = 0; nt < 4; ++nt) {
        acc[nt] = (f32x4)(0.f);
        const unsigned short* wp = Wt + (((size_t)h * 64 + nt * 16 + r) * 64 + grp * 8);
        const f16x8 b0 = *(const f16x8*)wp;
        const f16x8 b1 = *(const f16x8*)(wp + 32);
        acc[nt] = __builtin_amdgcn_mfma_f32_16x16x32_f16(b0, a0, acc[nt], 0, 0, 0);
        acc[nt] = __builtin_amdgcn_mfma_f32_16x16x32_f16(b1, a1, acc[nt], 0, 0, 0);
    }
    if (i < N) {
        float* orow = out + ((size_t)i * H + h) * 64;
#pragma unroll
        for (int nt = 0; nt < 4; ++nt) {
            float4 o;
            o.x = fmaxf(acc[nt][0], 0.f); o.y = fmaxf(acc[nt][1], 0.f);
            o.z = fmaxf(acc[nt][2], 0.f); o.w = fmaxf(acc[nt][3], 0.f);
            *(float4*)(orow + nt * 16 + grp * 4) = o;
        }
    }
}

extern "C" void kernel_launch(void* const* d_in, const int* in_sizes, int n_in,
                              void* d_out, int out_size, void* d_ws, size_t ws_size,
                              hipStream_t stream) {
    const float* nf     = (const float*)d_in[0];
    const float* W      = (const float*)d_in[1];
    const float* a_pos  = (const float*)d_in[2];
    const float* a_neg  = (const float*)d_in[3];
    const float* ee     = (const float*)d_in[4];
    const float* et     = (const float*)d_in[5];
    const int* unique_nodes = (const int*)d_in[6];
    const int* pos_col  = (const int*)d_in[9];
    const int* neg_col  = (const int*)d_in[11];

    const int U    = in_sizes[6];
    const int N    = in_sizes[7];
    const int Epos = in_sizes[8];
    const int Eneg = in_sizes[10];
    const int H    = in_sizes[1] / (64 * 64);
    const int DEGN = Eneg / N;
    const int DEGP = Epos / N - 1;
    const int ET   = in_sizes[4] / 64;

    char* ws = (char*)d_ws;
    auto alloc = [&](size_t bytes) { char* p = ws; ws += (bytes + 255) & ~(size_t)255; return p; };
    unsigned short* elo    = (unsigned short*)alloc((size_t)U * 32 * 2);
    unsigned short* ehi    = (unsigned short*)alloc((size_t)U * 32 * 2);
    float2*         sc_dst = (float2*)alloc((size_t)U * H * 8);
    float2*         sc_src = (float2*)alloc((size_t)U * H * 8);
    unsigned short* aggb   = (unsigned short*)alloc((size_t)N * H * 64 * 2);
    unsigned short* Wt     = (unsigned short*)alloc((size_t)H * 4096 * 2);
    unsigned short* avB    = (unsigned short*)alloc((size_t)H * 256 * 2);
    float* out = (float*)d_out;

    const int PT = H * 4096 + H * 256 + ET * 64;
    prep_kernel<<<(PT + 255) / 256, 256, 0, stream>>>(W, a_pos, a_neg, ee, et, Wt, avB,
                                                      out + (size_t)N * H * 64, H, ET);

    if (H == 4 && DEGP == 16 && DEGN == 16 && (N % 16) == 0) {
        score_cvt_kernel<<<(U + 63) / 64, 256, 0, stream>>>(nf, avB, unique_nodes,
                                                            elo, ehi, sc_dst, sc_src, U);
        aggemm_kernel<<<N / 16, 512, 0, stream>>>(pos_col, neg_col, elo, ehi,
                                                  sc_dst, sc_src, Wt, out, N, U);
    } else {
        embed_cvt_generic<<<(int)(((long)U * 64 + 255) / 256), 256, 0, stream>>>(
            nf, unique_nodes, elo, ehi, U);
        score_generic<<<(int)(((long)U * H + 255) / 256), 256, 0, stream>>>(
            elo, ehi, avB, sc_dst, sc_src, U, H);
        agg_generic<<<(int)(((long)N * H + 3) / 4), 256, 0, stream>>>(
            pos_col, neg_col, elo, ehi, sc_dst, sc_src, aggb, N, U, DEGP, DEGN, H);
        const long tiles = ((long)N + 15) / 16;
        out_gemm_generic<<<(int)((tiles * H + 3) / 4), 256, 0, stream>>>(aggb, Wt, out, N, H);
    }
}

// Round 14
// 45.555 us; speedup vs baseline: 1.1341x; 1.1034x over previous
//
#include <hip/hip_runtime.h>
#include <hip/hip_bf16.h>
#include <hip/hip_fp16.h>
#include <math.h>

#define LRELU_ALPHA 0.2f

typedef __attribute__((ext_vector_type(8))) short bf16x8;
typedef __attribute__((ext_vector_type(4))) float f32x4;
typedef _Float16 f16x8 __attribute__((ext_vector_type(8)));

__device__ __forceinline__ unsigned short f2bf(float f) {
    union { float f; unsigned u; } v; v.f = f;
    unsigned r = v.u + 0x7fffu + ((v.u >> 16) & 1u);
    return (unsigned short)(r >> 16);
}
__device__ __forceinline__ unsigned short f2h(float f) {
    union { __half h; unsigned short s; } c; c.h = __float2half_rn(f); return c.s;
}
__device__ __forceinline__ unsigned cvtpk(float lo, float hi) {
    unsigned r;
    asm("v_cvt_pk_bf16_f32 %0, %1, %2" : "=v"(r) : "v"(lo), "v"(hi));
    return r;
}
__device__ __forceinline__ __half2 u2h2(unsigned u) {
    union { unsigned u; __half2 h; } x; x.u = u; return x.h;
}
__device__ __forceinline__ unsigned h22u(__half2 h) {
    union { __half2 h; unsigned u; } x; x.h = h; return x.u;
}
__device__ __forceinline__ float2 upk(unsigned u) {   // f16 pair -> f32 pair
    return __half22float2(u2h2(u));
}

// ---------------- K0 prep: Wt(f16) + avB(bf16) + edge_out ---------------------------
__global__ void prep_kernel(const float* __restrict__ W,
                            const float* __restrict__ a_pos, const float* __restrict__ a_neg,
                            const float* __restrict__ ee, const float* __restrict__ et,
                            unsigned short* __restrict__ Wt, unsigned short* __restrict__ avB,
                            float* __restrict__ edge_out, int H, int ET) {
    const int HE = H * 4096, AV = H * 256;
    int t = blockIdx.x * blockDim.x + threadIdx.x;
    if (t < HE) {
        int k = t & 63, n = (t >> 6) & 63, h = t >> 12;
        Wt[((size_t)h * 64 + n) * 64 + k] = f2h(W[(size_t)h * 4096 + k * 64 + n]);
    } else if (t < HE + AV) {
        int s = t - HE;
        int k = s & 63, q = (s >> 6) & 3, h = s >> 8;
        const float* a  = (q < 2 ? a_pos : a_neg) + (size_t)h * 128 + (q & 1) * 64;
        const float* wr = W + (size_t)h * 4096 + k * 64;
        float v = 0.f;
#pragma unroll
        for (int o = 0; o < 64; o += 4) {
            const float4 wv = *(const float4*)(wr + o);
            const float4 av = *(const float4*)(a + o);
            v = fmaf(wv.x, av.x, fmaf(wv.y, av.y, fmaf(wv.z, av.z, fmaf(wv.w, av.w, v))));
        }
        avB[((size_t)h * 4 + q) * 64 + k] = f2bf(v);
    } else {
        int s = t - HE - AV;
        if (s < ET * 64) {
            int e = s >> 6, o = s & 63;
            float acc = 0.f;
#pragma unroll
            for (int k = 0; k < 64; ++k)
                acc = fmaf(ee[e * 64 + k], et[k * 64 + o], acc);
            edge_out[s] = acc;
        }
    }
}

// ---------------- K1 (H==4): embed f32->f16 + score MFMA (f16-packed scores) --------
// scd[u*4+h] = f16pair{pd,nd};  scs[u*4+h] = f16pair{ps,ns}
__global__ __launch_bounds__(256) void score_cvt_kernel(
    const float* __restrict__ nf, const unsigned short* __restrict__ avB,
    const int* __restrict__ un, unsigned short* __restrict__ embed16,
    unsigned* __restrict__ scd, unsigned* __restrict__ scs, int U)
{
    const int wave = threadIdx.x >> 6;
    const int lane = threadIdx.x & 63;
    const int grp  = lane >> 4;
    const int r    = lane & 15;
    const long u0  = (long)blockIdx.x * 64 + wave * 16;
    if (u0 >= U) return;
    const long u  = u0 + r;
    const long ur = (u < U) ? u : (long)(U - 1);

    const float* erow = nf + (size_t)un[ur] * 64 + grp * 8;
    const float4 e0 = *(const float4*)(erow);
    const float4 e1 = *(const float4*)(erow + 4);
    const float4 e2 = *(const float4*)(erow + 32);
    const float4 e3 = *(const float4*)(erow + 36);

    union { unsigned d[4]; bf16x8 v; } A0, A1;
    A0.d[0] = cvtpk(e0.x, e0.y); A0.d[1] = cvtpk(e0.z, e0.w);
    A0.d[2] = cvtpk(e1.x, e1.y); A0.d[3] = cvtpk(e1.z, e1.w);
    A1.d[0] = cvtpk(e2.x, e2.y); A1.d[1] = cvtpk(e2.z, e2.w);
    A1.d[2] = cvtpk(e3.x, e3.y); A1.d[3] = cvtpk(e3.z, e3.w);

    if (u < U) {
        union { __half2 h2[4]; uint4 v; } F0, F1;
        F0.h2[0] = __floats2half2_rn(e0.x, e0.y); F0.h2[1] = __floats2half2_rn(e0.z, e0.w);
        F0.h2[2] = __floats2half2_rn(e1.x, e1.y); F0.h2[3] = __floats2half2_rn(e1.z, e1.w);
        F1.h2[0] = __floats2half2_rn(e2.x, e2.y); F1.h2[1] = __floats2half2_rn(e2.z, e2.w);
        F1.h2[2] = __floats2half2_rn(e3.x, e3.y); F1.h2[3] = __floats2half2_rn(e3.z, e3.w);
        *(uint4*)(embed16 + (size_t)u * 64 + grp * 8)      = F0.v;
        *(uint4*)(embed16 + (size_t)u * 64 + 32 + grp * 8) = F1.v;
    }

    f32x4 acc = (f32x4)(0.f);
    const unsigned short* wp = avB + (size_t)r * 64 + grp * 8;
    bf16x8 b0 = *(const bf16x8*)wp;
    bf16x8 b1 = *(const bf16x8*)(wp + 32);
    acc = __builtin_amdgcn_mfma_f32_16x16x32_bf16(b0, A0.v, acc, 0, 0, 0);
    acc = __builtin_amdgcn_mfma_f32_16x16x32_bf16(b1, A1.v, acc, 0, 0, 0);

    if (u < U) {   // lane (grp=h, r): q = j -> {pd, ps, nd, ns}
        scd[(size_t)u * 4 + grp] = h22u(__floats2half2_rn(acc[0], acc[2]));  // {pd, nd}
        scs[(size_t)u * 4 + grp] = h22u(__floats2half2_rn(acc[1], acc[3]));  // {ps, ns}
    }
}

// ---------------- K2 fused (H==4, DEG 16/16, N%16==0): agg + out GEMM ---------------
// Block = 512 thr (8 waves) = 16 rows, wave = 2 rows (proven 47.6us structure).
// Scores: ONE uint4 (16B) per edge (src) + ONE uint4 per row (dst) — f16 pairs.
// MAC: 9 iters, lane = (sub = edge subgroup 0..3, c = 8B chunk 0..15), uint2 gathers.
// Phase 2: waves 0-3 = head h: 16x64 @ 64x64 f16 MFMA from LDS, relu, store.
__global__ __launch_bounds__(512) void aggemm_kernel(
    const int* __restrict__ pos_col, const int* __restrict__ neg_col,
    const unsigned short* __restrict__ embed16,
    const unsigned* __restrict__ scd, const unsigned* __restrict__ scs,
    const unsigned short* __restrict__ Wt,
    float* __restrict__ out, int N, int U)
{
    constexpr int DP = 16, NE = 33, NEP = 36;
    __shared__ int   s_col[8][2][NEP];
    __shared__ uint4 s_att[8][2][NEP];
    __shared__ __align__(16) unsigned short s_agg[16][256];  // [row][h*64+dim] f16

    const int wave = threadIdx.x >> 6;
    const int lane = threadIdx.x & 63;
    const int iA = blockIdx.x * 16 + wave * 2;
    const int iB = iA + 1;

    // ---- cols for both rows (lane = edge id; pads col=0)
    int colA = 0, colB = 0;
    if (lane < DP)       { colA = pos_col[(size_t)iA * DP + lane];
                           colB = pos_col[(size_t)iB * DP + lane]; }
    else if (lane == DP) { colA = pos_col[(size_t)N * DP + iA];
                           colB = pos_col[(size_t)N * DP + iB]; }
    else if (lane < NE)  { colA = neg_col[(size_t)iA * 16 + (lane - DP - 1)];
                           colB = neg_col[(size_t)iB * 16 + (lane - DP - 1)]; }

    // ---- scores: one 16B src load per edge, one 16B dst load per row
    const uint4 svA = *(const uint4*)(scs + (size_t)(unsigned)colA * 4);
    const uint4 svB = *(const uint4*)(scs + (size_t)(unsigned)colB * 4);
    const int uA = __shfl(colA, DP, 64), uB = __shfl(colB, DP, 64);
    const uint4 dvA = *(const uint4*)(scd + (size_t)(unsigned)uA * 4);
    const uint4 dvB = *(const uint4*)(scd + (size_t)(unsigned)uB * 4);

    // per head: {pos_score, neg_score} = dst{pd,nd} + src{ps,ns} (f32 add)
    const bool isp = (lane <= DP);
    float2 sA_0 = upk(svA.x), sA_1 = upk(svA.y), sA_2 = upk(svA.z), sA_3 = upk(svA.w);
    float2 sB_0 = upk(svB.x), sB_1 = upk(svB.y), sB_2 = upk(svB.z), sB_3 = upk(svB.w);
    float2 dA_0 = upk(dvA.x), dA_1 = upk(dvA.y), dA_2 = upk(dvA.z), dA_3 = upk(dvA.w);
    float2 dB_0 = upk(dvB.x), dB_1 = upk(dvB.y), dB_2 = upk(dvB.z), dB_3 = upk(dvB.w);
    float a_s0 = isp ? dA_0.x + sA_0.x : dA_0.y + sA_0.y;
    float a_s1 = isp ? dA_1.x + sA_1.x : dA_1.y + sA_1.y;
    float a_s2 = isp ? dA_2.x + sA_2.x : dA_2.y + sA_2.y;
    float a_s3 = isp ? dA_3.x + sA_3.x : dA_3.y + sA_3.y;
    float b_s0 = isp ? dB_0.x + sB_0.x : dB_0.y + sB_0.y;
    float b_s1 = isp ? dB_1.x + sB_1.x : dB_1.y + sB_1.y;
    float b_s2 = isp ? dB_2.x + sB_2.x : dB_2.y + sB_2.y;
    float b_s3 = isp ? dB_3.x + sB_3.x : dB_3.y + sB_3.y;
    a_s0 = (a_s0 > 0.f) ? a_s0 : LRELU_ALPHA * a_s0;
    a_s1 = (a_s1 > 0.f) ? a_s1 : LRELU_ALPHA * a_s1;
    a_s2 = (a_s2 > 0.f) ? a_s2 : LRELU_ALPHA * a_s2;
    a_s3 = (a_s3 > 0.f) ? a_s3 : LRELU_ALPHA * a_s3;
    b_s0 = (b_s0 > 0.f) ? b_s0 : LRELU_ALPHA * b_s0;
    b_s1 = (b_s1 > 0.f) ? b_s1 : LRELU_ALPHA * b_s1;
    b_s2 = (b_s2 > 0.f) ? b_s2 : LRELU_ALPHA * b_s2;
    b_s3 = (b_s3 > 0.f) ? b_s3 : LRELU_ALPHA * b_s3;

    // exp WITHOUT max-subtract (scores are O(1); f32 exp cannot overflow here)
    const bool act = (lane < NE);
    float ax0 = act ? __expf(a_s0) : 0.f, ax1 = act ? __expf(a_s1) : 0.f;
    float ax2 = act ? __expf(a_s2) : 0.f, ax3 = act ? __expf(a_s3) : 0.f;
    float bx0 = act ? __expf(b_s0) : 0.f, bx1 = act ? __expf(b_s1) : 0.f;
    float bx2 = act ? __expf(b_s2) : 0.f, bx3 = act ? __expf(b_s3) : 0.f;
    float aS0 = ax0, aS1 = ax1, aS2 = ax2, aS3 = ax3;
    float bS0 = bx0, bS1 = bx1, bS2 = bx2, bS3 = bx3;
#pragma unroll
    for (int off = 32; off; off >>= 1) {
        aS0 += __shfl_xor(aS0, off, 64); aS1 += __shfl_xor(aS1, off, 64);
        aS2 += __shfl_xor(aS2, off, 64); aS3 += __shfl_xor(aS3, off, 64);
        bS0 += __shfl_xor(bS0, off, 64); bS1 += __shfl_xor(bS1, off, 64);
        bS2 += __shfl_xor(bS2, off, 64); bS3 += __shfl_xor(bS3, off, 64);
    }
    if (lane < NEP) {   // lanes 33..35: col=0, att=0
        uint4 tA, tB;
        tA.x = h22u(__float2half2_rn(__fdividef(ax0, aS0)));
        tA.y = h22u(__float2half2_rn(__fdividef(ax1, aS1)));
        tA.z = h22u(__float2half2_rn(__fdividef(ax2, aS2)));
        tA.w = h22u(__float2half2_rn(__fdividef(ax3, aS3)));
        tB.x = h22u(__float2half2_rn(__fdividef(bx0, bS0)));
        tB.y = h22u(__float2half2_rn(__fdividef(bx1, bS1)));
        tB.z = h22u(__float2half2_rn(__fdividef(bx2, bS2)));
        tB.w = h22u(__float2half2_rn(__fdividef(bx3, bS3)));
        s_col[wave][0][lane] = colA;  s_att[wave][0][lane] = tA;
        s_col[wave][1][lane] = colB;  s_att[wave][1][lane] = tB;
    }
    // wave-private LDS slice: same-wave ordering, no barrier needed

    // ---- MAC: 9 iters x 2 rows; lane = (sub = edge subgroup 0..3, c = 8B chunk 0..15)
    const int sub = lane >> 4;
    const int c   = lane & 15;
    const char* eb = (const char*)embed16 + (c << 3);
    __half2 accA[4][2], accB[4][2];
#pragma unroll
    for (int h = 0; h < 4; ++h)
#pragma unroll
        for (int d = 0; d < 2; ++d) {
            accA[h][d] = __float2half2_rn(0.f);
            accB[h][d] = __float2half2_rn(0.f);
        }
#pragma unroll
    for (int t = 0; t < 9; ++t) {
        const int   e  = 4 * t + sub;
        const int   cA = s_col[wave][0][e];
        const int   cB = s_col[wave][1][e];
        const uint2 vA = *(const uint2*)(eb + ((size_t)(unsigned)cA << 7));
        const uint2 vB = *(const uint2*)(eb + ((size_t)(unsigned)cB << 7));
        const uint4 tA = s_att[wave][0][e];
        const uint4 tB = s_att[wave][1][e];
        const __half2 vA0 = u2h2(vA.x), vA1 = u2h2(vA.y);
        const __half2 vB0 = u2h2(vB.x), vB1 = u2h2(vB.y);
        accA[0][0] = __hfma2(u2h2(tA.x), vA0, accA[0][0]);
        accA[0][1] = __hfma2(u2h2(tA.x), vA1, accA[0][1]);
        accA[1][0] = __hfma2(u2h2(tA.y), vA0, accA[1][0]);
        accA[1][1] = __hfma2(u2h2(tA.y), vA1, accA[1][1]);
        accA[2][0] = __hfma2(u2h2(tA.z), vA0, accA[2][0]);
        accA[2][1] = __hfma2(u2h2(tA.z), vA1, accA[2][1]);
        accA[3][0] = __hfma2(u2h2(tA.w), vA0, accA[3][0]);
        accA[3][1] = __hfma2(u2h2(tA.w), vA1, accA[3][1]);
        accB[0][0] = __hfma2(u2h2(tB.x), vB0, accB[0][0]);
        accB[0][1] = __hfma2(u2h2(tB.x), vB1, accB[0][1]);
        accB[1][0] = __hfma2(u2h2(tB.y), vB0, accB[1][0]);
        accB[1][1] = __hfma2(u2h2(tB.y), vB1, accB[1][1]);
        accB[2][0] = __hfma2(u2h2(tB.z), vB0, accB[2][0]);
        accB[2][1] = __hfma2(u2h2(tB.z), vB1, accB[2][1]);
        accB[3][0] = __hfma2(u2h2(tB.w), vB0, accB[3][0]);
        accB[3][1] = __hfma2(u2h2(tB.w), vB1, accB[3][1]);
    }
    // reduce across the 4 edge subgroups (lanes differing in bits 4,5)
#pragma unroll
    for (int h = 0; h < 4; ++h)
#pragma unroll
        for (int d = 0; d < 2; ++d) {
            unsigned ua = h22u(accA[h][d]);
            ua = h22u(__hadd2(u2h2(ua), u2h2((unsigned)__shfl_xor((int)ua, 16, 64))));
            ua = h22u(__hadd2(u2h2(ua), u2h2((unsigned)__shfl_xor((int)ua, 32, 64))));
            accA[h][d] = u2h2(ua);
            unsigned ub = h22u(accB[h][d]);
            ub = h22u(__hadd2(u2h2(ub), u2h2((unsigned)__shfl_xor((int)ub, 16, 64))));
            ub = h22u(__hadd2(u2h2(ub), u2h2((unsigned)__shfl_xor((int)ub, 32, 64))));
            accB[h][d] = u2h2(ub);
        }
    if (sub == 0) {   // lanes 0-15: write f16 agg rows (dims 4c..4c+3 per head)
#pragma unroll
        for (int h = 0; h < 4; ++h) {
            uint2 wA, wB;
            wA.x = h22u(accA[h][0]); wA.y = h22u(accA[h][1]);
            wB.x = h22u(accB[h][0]); wB.y = h22u(accB[h][1]);
            *(uint2*)((char*)&s_agg[wave * 2][h * 64] + c * 8)     = wA;
            *(uint2*)((char*)&s_agg[wave * 2 + 1][h * 64] + c * 8) = wB;
        }
    }
    __syncthreads();

    // ---- phase 2: waves 0-3 = head h; 16 rows x 64 dims f16 MFMA, relu, store
    if (wave < 4) {
        const int h   = wave;
        const int grp = lane >> 4;
        const int r   = lane & 15;
        const f16x8 a0 = *(const f16x8*)((const char*)&s_agg[r][h * 64] + grp * 16);
        const f16x8 a1 = *(const f16x8*)((const char*)&s_agg[r][h * 64 + 32] + grp * 16);
        f32x4 acc[4];
#pragma unroll
        for (int nt = 0; nt < 4; ++nt) {
            acc[nt] = (f32x4)(0.f);
            const unsigned short* wp = Wt + (((size_t)h * 64 + nt * 16 + r) * 64 + grp * 8);
            const f16x8 b0 = *(const f16x8*)wp;
            const f16x8 b1 = *(const f16x8*)(wp + 32);
            acc[nt] = __builtin_amdgcn_mfma_f32_16x16x32_f16(b0, a0, acc[nt], 0, 0, 0);
            acc[nt] = __builtin_amdgcn_mfma_f32_16x16x32_f16(b1, a1, acc[nt], 0, 0, 0);
        }
        float* orow = out + ((size_t)(blockIdx.x * 16 + r) * 4 + h) * 64;
#pragma unroll
        for (int nt = 0; nt < 4; ++nt) {
            float4 o;
            o.x = fmaxf(acc[nt][0], 0.f); o.y = fmaxf(acc[nt][1], 0.f);
            o.z = fmaxf(acc[nt][2], 0.f); o.w = fmaxf(acc[nt][3], 0.f);
            *(float4*)(orow + nt * 16 + grp * 4) = o;
        }
    }
}

// ---------------- generic fallbacks (correctness-only, any shape) -------------------
__global__ void embed_cvt_generic(const float* __restrict__ nf, const int* __restrict__ un,
                                  unsigned short* __restrict__ embed16, int U) {
    long t = (long)blockIdx.x * blockDim.x + threadIdx.x;
    if (t >= (long)U * 64) return;
    embed16[t] = f2h(nf[(size_t)un[t >> 6] * 64 + (t & 63)]);
}
__global__ void score_generic(const unsigned short* __restrict__ embed16,
                              const unsigned short* __restrict__ avB,
                              unsigned* __restrict__ scd, unsigned* __restrict__ scs,
                              int U, int H) {
    long t = (long)blockIdx.x * blockDim.x + threadIdx.x;
    if (t >= (long)U * H) return;
    const long u = t / H; const int h = (int)(t % H);
    float s[4];
    for (int q = 0; q < 4; ++q) {
        float acc = 0.f;
        for (int k = 0; k < 64; ++k) {
            union { unsigned short s; __half h; } w; w.s = embed16[u * 64 + k];
            union { unsigned uu; float f; } b;
            b.uu = ((unsigned)avB[((size_t)h * 4 + q) * 64 + k]) << 16;
            acc = fmaf(__half2float(w.h), b.f, acc);
        }
        s[q] = acc;
    }
    scd[u * H + h] = h22u(__floats2half2_rn(s[0], s[2]));
    scs[u * H + h] = h22u(__floats2half2_rn(s[1], s[3]));
}
__global__ __launch_bounds__(256) void agg_generic(
    const int* __restrict__ pos_col, const int* __restrict__ neg_col,
    const unsigned short* __restrict__ embed16,
    const unsigned* __restrict__ scd, const unsigned* __restrict__ scs,
    unsigned short* __restrict__ aggb, int N, int U, int DEGP, int DEGN, int H)
{
    const int wave = threadIdx.x >> 6;
    const int lane = threadIdx.x & 63;
    const long j = (long)blockIdx.x * 4 + wave;
    const int i = (int)(j % N);
    const int h = (int)(j / N);
    if (h >= H) return;
    const int NE = DEGP + 1 + DEGN;

    int col = 0;
    if (lane < DEGP)       col = pos_col[(size_t)i * DEGP + lane];
    else if (lane == DEGP) col = pos_col[(size_t)N * DEGP + i];
    else if (lane < NE)    col = neg_col[(size_t)i * DEGN + (lane - DEGP - 1)];
    const float2 ss = upk(scs[(size_t)col * H + h]);
    const int u0s = __shfl(col, DEGP, 64);
    const float2 sd = upk(scd[(size_t)u0s * H + h]);
    float score = -INFINITY;
    if (lane < NE) {
        const float raw = (lane <= DEGP) ? sd.x + ss.x : sd.y + ss.y;
        score = (raw > 0.f) ? raw : LRELU_ALPHA * raw;
    }
    float m = score;
#pragma unroll
    for (int off = 32; off; off >>= 1) m = fmaxf(m, __shfl_xor(m, off, 64));
    const float ex = (lane < NE) ? __expf(score - m) : 0.f;
    float S = ex;
#pragma unroll
    for (int off = 32; off; off >>= 1) S += __shfl_xor(S, off, 64);
    const float att = __fdividef(ex, S);

    float acc = 0.f;
    for (int e = 0; e < NE; ++e) {
        const int   ce = __shfl(col, e, 64);
        const float ae = __shfl(att, e, 64);
        union { unsigned short s; __half h; } w;
        w.s = embed16[(size_t)(unsigned)ce * 64 + lane];
        acc = fmaf(ae, __half2float(w.h), acc);
    }
    aggb[((size_t)i * H + h) * 64 + lane] = f2h(acc);
}
__global__ __launch_bounds__(256) void out_gemm_generic(
    const unsigned short* __restrict__ aggb, const unsigned short* __restrict__ Wt,
    float* __restrict__ out, int N, int H)
{
    const int wave = threadIdx.x >> 6;
    const int lane = threadIdx.x & 63;
    const int grp  = lane >> 4;
    const int r    = lane & 15;
    const long j = (long)blockIdx.x * 4 + wave;
    const int  h = (int)(j % H);
    const long i0 = (j / H) * 16;
    if (i0 >= N) return;
    const long i  = i0 + r;
    const long ir = (i < N) ? i : (long)(N - 1);

    const unsigned short* arow = aggb + ((size_t)ir * H + h) * 64 + grp * 8;
    const f16x8 a0 = *(const f16x8*)arow;
    const f16x8 a1 = *(const f16x8*)(arow + 32);
    f32x4 acc[4];
#pragma unroll
    for (int nt = 0; nt < 4; ++nt) {
        acc[nt] = (f32x4)(0.f);
        const unsigned short* wp = Wt + (((size_t)h * 64 + nt * 16 + r) * 64 + grp * 8);
        const f16x8 b0 = *(const f16x8*)wp;
        const f16x8 b1 = *(const f16x8*)(wp + 32);
        acc[nt] = __builtin_amdgcn_mfma_f32_16x16x32_f16(b0, a0, acc[nt], 0, 0, 0);
        acc[nt] = __builtin_amdgcn_mfma_f32_16x16x32_f16(b1, a1, acc[nt], 0, 0, 0);
    }
    if (i < N) {
        float* orow = out + ((size_t)i * H + h) * 64;
#pragma unroll
        for (int nt = 0; nt < 4; ++nt) {
            float4 o;
            o.x = fmaxf(acc[nt][0], 0.f); o.y = fmaxf(acc[nt][1], 0.f);
            o.z = fmaxf(acc[nt][2], 0.f); o.w = fmaxf(acc[nt][3], 0.f);
            *(float4*)(orow + nt * 16 + grp * 4) = o;
        }
    }
}

extern "C" void kernel_launch(void* const* d_in, const int* in_sizes, int n_in,
                              void* d_out, int out_size, void* d_ws, size_t ws_size,
                              hipStream_t stream) {
    const float* nf     = (const float*)d_in[0];
    const float* W      = (const float*)d_in[1];
    const float* a_pos  = (const float*)d_in[2];
    const float* a_neg  = (const float*)d_in[3];
    const float* ee     = (const float*)d_in[4];
    const float* et     = (const float*)d_in[5];
    const int* unique_nodes = (const int*)d_in[6];
    const int* pos_col  = (const int*)d_in[9];
    const int* neg_col  = (const int*)d_in[11];

    const int U    = in_sizes[6];
    const int N    = in_sizes[7];
    const int Epos = in_sizes[8];
    const int Eneg = in_sizes[10];
    const int H    = in_sizes[1] / (64 * 64);
    const int DEGN = Eneg / N;
    const int DEGP = Epos / N - 1;
    const int ET   = in_sizes[4] / 64;

    char* ws = (char*)d_ws;
    auto alloc = [&](size_t bytes) { char* p = ws; ws += (bytes + 255) & ~(size_t)255; return p; };
    unsigned short* embed16 = (unsigned short*)alloc((size_t)U * 64 * 2);
    unsigned*       scd     = (unsigned*)alloc((size_t)U * H * 4);
    unsigned*       scs     = (unsigned*)alloc((size_t)U * H * 4);
    unsigned short* aggb    = (unsigned short*)alloc((size_t)N * H * 64 * 2);
    unsigned short* Wt      = (unsigned short*)alloc((size_t)H * 4096 * 2);
    unsigned short* avB     = (unsigned short*)alloc((size_t)H * 256 * 2);
    float* out = (float*)d_out;

    const int PT = H * 4096 + H * 256 + ET * 64;
    prep_kernel<<<(PT + 255) / 256, 256, 0, stream>>>(W, a_pos, a_neg, ee, et, Wt, avB,
                                                      out + (size_t)N * H * 64, H, ET);

    if (H == 4 && DEGP == 16 && DEGN == 16 && (N % 16) == 0) {
        score_cvt_kernel<<<(U + 63) / 64, 256, 0, stream>>>(nf, avB, unique_nodes,
                                                            embed16, scd, scs, U);
        aggemm_kernel<<<N / 16, 512, 0, stream>>>(pos_col, neg_col, embed16,
                                                  scd, scs, Wt, out, N, U);
    } else {
        embed_cvt_generic<<<(int)(((long)U * 64 + 255) / 256), 256, 0, stream>>>(
            nf, unique_nodes, embed16, U);
        score_generic<<<(int)(((long)U * H + 255) / 256), 256, 0, stream>>>(
            embed16, avB, scd, scs, U, H);
        agg_generic<<<(int)(((long)N * H + 3) / 4), 256, 0, stream>>>(
            pos_col, neg_col, embed16, scd, scs, aggb, N, U, DEGP, DEGN, H);
        const long tiles = ((long)N + 15) / 16;
        out_gemm_generic<<<(int)((tiles * H + 3) / 4), 256, 0, stream>>>(aggb, Wt, out, N, H);
    }
}